// Round 18
// baseline (436.122 us; speedup 1.0000x reference)
//
#include <hip/hip_runtime.h>
#include <hip/hip_bf16.h>
#include <stdint.h>

#define B_ 4
#define S_ 2048
#define D_ 2048
#define H_ 16
#define DH_ 128

typedef short bf8_t __attribute__((ext_vector_type(8)));   // 8 bf16 (4 VGPRs)
typedef float f4_t  __attribute__((ext_vector_type(4)));   // MFMA C/D

__device__ __forceinline__ unsigned short f2bf(float f) {
  __hip_bfloat16 h = __float2bfloat16(f);   // RNE
  return *reinterpret_cast<const unsigned short*>(&h);
}
__device__ __forceinline__ float bf2f(unsigned short u) {
  return __uint_as_float(((unsigned int)u) << 16);
}

// async global->LDS, 16B per lane. LDS dest must be (wave-uniform base + lane*16).
__device__ __forceinline__ void gload_lds16(const void* g, void* lds) {
  __builtin_amdgcn_global_load_lds(
      (const __attribute__((address_space(1))) unsigned int*)(uintptr_t)g,
      (__attribute__((address_space(3))) unsigned int*)(unsigned int)(uintptr_t)lds,
      16, 0, 0);
}

// ---------------- fused f32 -> bf16 conversion, grid-stride ----------------
__global__ __launch_bounds__(256) void conv_all(
    const float* __restrict__ x, const float* __restrict__ wqkv,
    const float* __restrict__ wo, unsigned short* __restrict__ xb,
    unsigned short* __restrict__ wqkvb, unsigned short* __restrict__ wob) {
  const int NX = 4194304, NQ = 3145728;
  const int TOT = 8388608, STR = 2048 * 256;
  for (int idx = blockIdx.x * 256 + threadIdx.x; idx < TOT; idx += STR) {
    const float* in;
    unsigned short* out;
    int i;
    if (idx < NX)           { in = x;    out = xb;    i = idx; }
    else if (idx < NX + NQ) { in = wqkv; out = wqkvb; i = idx - NX; }
    else                    { in = wo;   out = wob;   i = idx - NX - NQ; }
    float4 v = ((const float4*)in)[i];
    ushort4 u;
    u.x = f2bf(v.x); u.y = f2bf(v.y); u.z = f2bf(v.z); u.w = f2bf(v.w);
    ((ushort4*)out)[i] = u;
  }
}

// ---------------- 256x256 GEMM, ring-4 (128 KB LDS), BK=32 ----------------
// Proven structure (1 phase/slice): vmcnt(8)+bar; 12 reads; STAGE(s+3);
// 32 MFMA. ~193 us QKV, MfmaUtil 48%, 0 bank conflicts. LDS-read-BW-bound:
// 24 b128/wave/tile x 8 waves = 192 KB/CU/tile (~1536 cy) vs ~620 cy MFMA.
// Schedule variants (ring-2, 2-phase, full 8-phase) all land 46-48%.
template <int EPI>
__global__ __launch_bounds__(512, 2) void gemm256(
    const unsigned short* __restrict__ A, const unsigned short* __restrict__ Bt,
    float* __restrict__ Cf, unsigned short* __restrict__ Cb,
    int M, int N, int K) {
  __shared__ unsigned short AB[4][2][8192];   // [ring][A,B][256 rows x 32 k] = 128 KB
  const int tid  = threadIdx.x;
  const int lane = tid & 63;
  const int wv   = tid >> 6;     // 0..7
  const int wr   = wv >> 2;      // 0..1  (M half)
  const int wc   = wv & 3;       // 0..3  (N quarter)
  const int rsel = lane & 15;
  const int g    = lane >> 4;
  const int qr0  = g * 4;

  // bijective XCD swizzle (nwg % 8 == 0 for all our grids)
  int id  = blockIdx.y * gridDim.x + blockIdx.x;
  int cpx = (gridDim.x * gridDim.y) >> 3;
  int swz = (id & 7) * cpx + (id >> 3);
  const int bm = (swz / gridDim.x) * 256;
  const int bn = (swz % gridDim.x) * 256;

  const int NS = K >> 5;   // BK=32 slices

  const int ob0 = tid * 16, ob1 = ob0 + 8192;
  const int row0 = ob0 >> 6, row1 = ob1 >> 6;
  const int g0 = ((ob0 >> 4) & 3) ^ ((row0 >> 1) & 3);
  const int g1 = ((ob1 >> 4) & 3) ^ ((row1 >> 1) & 3);
  const unsigned short* Ag0 = A + (size_t)(bm + row0) * K + g0 * 8;
  const unsigned short* Ag1 = A + (size_t)(bm + row1) * K + g1 * 8;
  const unsigned short* Bg0 = Bt + (size_t)(bn + row0) * K + g0 * 8;
  const unsigned short* Bg1 = Bt + (size_t)(bn + row1) * K + g1 * 8;

  f4_t acc[8][4];
#pragma unroll
  for (int i = 0; i < 8; ++i)
#pragma unroll
    for (int j = 0; j < 4; ++j) acc[i][j] = (f4_t){0.f, 0.f, 0.f, 0.f};

  int aoff[8], boff[4];
#pragma unroll
  for (int i = 0; i < 8; ++i) {
    int arow = wr * 128 + i * 16 + rsel;
    aoff[i] = arow * 64 + ((g * 16) ^ ((arow & 6) << 3));
  }
#pragma unroll
  for (int j = 0; j < 4; ++j) {
    int brow = wc * 64 + j * 16 + rsel;
    boff[j] = brow * 64 + ((g * 16) ^ ((brow & 6) << 3));
  }

#define STAGE(sl)                                                        \
  {                                                                      \
    int slot_ = (sl) & 3;                                                \
    int ks_   = (sl) << 5;                                               \
    gload_lds16(Ag0 + ks_, (char*)&AB[slot_][0][0] + ob0);               \
    gload_lds16(Ag1 + ks_, (char*)&AB[slot_][0][0] + ob1);               \
    gload_lds16(Bg0 + ks_, (char*)&AB[slot_][1][0] + ob0);               \
    gload_lds16(Bg1 + ks_, (char*)&AB[slot_][1][0] + ob1);               \
  }

  STAGE(0); STAGE(1); STAGE(2);   // 12 loads in flight

  for (int s = 0; s < NS; ++s) {
    if (s < NS - 2)       asm volatile("s_waitcnt vmcnt(8)" ::: "memory");
    else if (s == NS - 2) asm volatile("s_waitcnt vmcnt(4)" ::: "memory");
    else                  asm volatile("s_waitcnt vmcnt(0)" ::: "memory");
    __builtin_amdgcn_s_barrier();
    asm volatile("" ::: "memory");

    const char* As_ = (const char*)&AB[s & 3][0][0];
    const char* Bs_ = (const char*)&AB[s & 3][1][0];
    bf8_t af[8], bfr[4];
#pragma unroll
    for (int i = 0; i < 8; ++i) af[i] = *(const bf8_t*)(As_ + aoff[i]);
#pragma unroll
    for (int j = 0; j < 4; ++j) bfr[j] = *(const bf8_t*)(Bs_ + boff[j]);

    if (s + 3 < NS) STAGE(s + 3);   // safe: slot (s+3)&3 last read in iter s-1

    __builtin_amdgcn_s_setprio(1);
#pragma unroll
    for (int i = 0; i < 8; ++i)
#pragma unroll
      for (int j = 0; j < 4; ++j)
        acc[i][j] = __builtin_amdgcn_mfma_f32_16x16x32_bf16(af[i], bfr[j], acc[i][j], 0, 0, 0);
    __builtin_amdgcn_s_setprio(0);
  }
#undef STAGE

#pragma unroll
  for (int i = 0; i < 8; ++i) {
#pragma unroll
    for (int j = 0; j < 4; ++j) {
#pragma unroll
      for (int r = 0; r < 4; ++r) {
        int row = bm + wr * 128 + i * 16 + qr0 + r;
        int col = bn + wc * 64 + j * 16 + rsel;
        float v = acc[i][j][r];
        if (EPI == 0) {
          Cf[(size_t)row * N + col] = v;
        } else {
          int c = col >> 11, h = (col >> 7) & (H_ - 1), dh = col & (DH_ - 1);
          int b = row >> 11, s = row & (S_ - 1);
          size_t dst = ((((size_t)c * B_ + b) * H_ + h) * S_ + s) * DH_ + dh;
          Cb[dst] = f2bf(v);
        }
      }
    }
  }
}

// ---------------- RoPE tables ----------------
__global__ void rope_tab(float* __restrict__ tc, float* __restrict__ ts) {
  int s = blockIdx.x;
  int i = threadIdx.x;   // 64 threads
  float inv = powf(10000.0f, -(float)i / 64.0f);
  float f   = (float)s * inv;
  tc[s * 64 + i] = cosf(f);
  ts[s * 64 + i] = sinf(f);
}

// ---------------- RoPE apply in-place on K only, bf16x8 vectorized ----------
__global__ __launch_bounds__(256) void rope_k(
    unsigned short* __restrict__ Kk,
    const float* __restrict__ tc, const float* __restrict__ ts) {
  int idx = blockIdx.x * 256 + threadIdx.x;   // 2^20 total
  int iv  = idx & 7;
  int s   = (idx >> 3) & (S_ - 1);
  int bh  = idx >> 14;                        // 0..63
  size_t base = ((size_t)bh * S_ + s) * DH_;
  int i0 = iv * 8;
  bf8_t x1 = *(const bf8_t*)&Kk[base + i0];
  bf8_t x2 = *(const bf8_t*)&Kk[base + i0 + 64];
  const float* tcp = tc + s * 64 + i0;
  const float* tsp = ts + s * 64 + i0;
  bf8_t y1, y2;
#pragma unroll
  for (int e = 0; e < 8; ++e) {
    float c = tcp[e], sn = tsp[e];
    float a = bf2f((unsigned short)x1[e]);
    float b = bf2f((unsigned short)x2[e]);
    y1[e] = (short)f2bf(a * c - b * sn);
    y2[e] = (short)f2bf(b * c + a * sn);
  }
  *(bf8_t*)&Kk[base + i0]      = y1;
  *(bf8_t*)&Kk[base + i0 + 64] = y2;
}

// ---------------- causal flash attention (r11 structure, Q-RoPE fused) ----
// Chunk pairing fix: with 1 block/CU and 2 sequential blocks per CU, map
// stream position to chunk as {7,6,5,4} then {0,1,2,3} so every CU's pair
// sums to 36 tiles (was 48/40/32/24 -> 2x imbalance).
__global__ __launch_bounds__(512) void attn_fwd(
    const unsigned short* __restrict__ Q, const unsigned short* __restrict__ Kk,
    const unsigned short* __restrict__ V, unsigned short* __restrict__ Z,
    const float* __restrict__ tabc, const float* __restrict__ tabs) {
  __shared__ unsigned short Ks[3][64 * 128];  // 48 KB ring, XOR-swizzled (src-side)
  __shared__ unsigned short Vt[2][128 * 64];  // 32 KB, [dh][kv], XOR-swizzled
  __shared__ unsigned short Pw[8][32 * 64];   // 32 KB, per-wave 32 rows, swizzled
  const int tid  = threadIdx.x;
  const int lane = tid & 63;
  const int wv   = tid >> 6;                  // 0..7

  int id  = blockIdx.y * gridDim.x + blockIdx.x;   // nwg = 512
  int x   = id & 7;
  int idx = id >> 3;                               // 0..63
  const int bh = x * 8 + (idx & 7);
  const int cidx  = idx >> 3;                      // 0..7 stream position
  const int chunk = (cidx < 4) ? (7 - cidx) : (cidx - 4);
  const int q0 = chunk * 256;

  const size_t base = (size_t)bh * S_ * DH_;
  const int rsel = lane & 15;
  const int g    = lane >> 4;
  const int kof  = g * 8;
  const int qr0  = g * 4;
  const int qlo  = q0 + wv * 32;
  const int qhi  = qlo + 31;
  const float sl2 = 0.08838834764831845f * 1.4426950408889634f;  // scale*log2(e)

  // Q A-frags for both row-groups: load raw, RoPE in-register, fold sl2.
  bf8_t aq[2][4];
#pragma unroll
  for (int rg = 0; rg < 2; ++rg) {
    const int qrow = qlo + rg * 16 + rsel;
#pragma unroll
    for (int kc = 0; kc < 4; ++kc)
      aq[rg][kc] = *(const bf8_t*)&Q[base + (size_t)qrow * DH_ + kc * 32 + kof];
    const float* tcr = tabc + (size_t)qrow * 64;
    const float* tsr = tabs + (size_t)qrow * 64;
#pragma unroll
    for (int kc = 0; kc < 2; ++kc)
#pragma unroll
      for (int e = 0; e < 8; ++e) {
        int i = kc * 32 + kof + e;   // dh in [0,64)
        float c  = tcr[i], sn = tsr[i];
        float x1 = bf2f((unsigned short)aq[rg][kc][e]);
        float x2 = bf2f((unsigned short)aq[rg][kc + 2][e]);
        aq[rg][kc][e]     = (short)f2bf((x1 * c - x2 * sn) * sl2);
        aq[rg][kc + 2][e] = (short)f2bf((x2 * c + x1 * sn) * sl2);
      }
  }

  bf8_t vones;
#pragma unroll
  for (int e = 0; e < 8; ++e) vones[e] = (short)0x3F80;

  f4_t o[2][9];   // [rg][0..7]=output frags, [rg][8]=row-sum (denominator)
#pragma unroll
  for (int rg = 0; rg < 2; ++rg)
#pragma unroll
    for (int nf = 0; nf < 9; ++nf) o[rg][nf] = (f4_t){0.f, 0.f, 0.f, 0.f};
  float mrow[2][4] = {{-3e30f, -3e30f, -3e30f, -3e30f},
                      {-3e30f, -3e30f, -3e30f, -3e30f}};
  const int nt = q0 / 64 + 4;   // kv tiles cover [0, q0+256); nt >= 4

  const int kvp = tid & 31;
  const int vc0 = (tid >> 5) * 8;

#define KSTAGE(tt)                                                            \
  {                                                                           \
    const unsigned short* gK_ = Kk + base + (size_t)(tt) * 64 * DH_;          \
    int slot_ = (tt) % 3;                                                     \
    _Pragma("unroll")                                                         \
    for (int c = 0; c < 2; ++c) {                                             \
      int ob = (c * 512 + tid) * 16;                                          \
      int row = ob >> 8;                                                      \
      int scol = (ob & 255) ^ ((row & 7) << 4);                               \
      gload_lds16(gK_ + (size_t)row * DH_ + (scol >> 1),                      \
                  (char*)&Ks[slot_][0] + ob);                                 \
    }                                                                         \
  }
#define VTWRITE(buf_)                                                         \
  {                                                                           \
    unsigned int* Vt32 = (unsigned int*)&Vt[buf_][0];                         \
    _Pragma("unroll")                                                         \
    for (int e = 0; e < 8; ++e) {                                             \
      unsigned int val = (unsigned short)vlo[e] |                             \
                         ((unsigned int)(unsigned short)vhi[e] << 16);        \
      Vt32[(vc0 + e) * 32 + (kvp ^ (e << 2))] = val;                          \
    }                                                                         \
  }

  bf8_t vlo, vhi;
  vlo = *(const bf8_t*)&V[base + (size_t)(2 * kvp) * DH_ + vc0];
  vhi = *(const bf8_t*)&V[base + (size_t)(2 * kvp + 1) * DH_ + vc0];
  KSTAGE(0);
  KSTAGE(1);              // nt >= 4 always
  VTWRITE(0);             // compiler waits V(0) only; K loads stay in flight

  for (int t = 0; t < nt; ++t) {
    const int curV = t & 1;
    const int curK = t % 3;
    const bool pfV = (t + 1 < nt);
    const bool pfK = (t + 2 < nt);

    if (pfV) asm volatile("s_waitcnt vmcnt(2)" ::: "memory");
    else     asm volatile("s_waitcnt vmcnt(0)" ::: "memory");
    asm volatile("s_waitcnt lgkmcnt(0)" ::: "memory");
    __builtin_amdgcn_s_barrier();
    asm volatile("" ::: "memory");

    if (pfV) {
      const unsigned short* gV = V + base + (size_t)(t + 1) * 64 * DH_;
      vlo = *(const bf8_t*)&gV[(size_t)(2 * kvp) * DH_ + vc0];
      vhi = *(const bf8_t*)&gV[(size_t)(2 * kvp + 1) * DH_ + vc0];
    }
    if (pfK) KSTAGE(t + 2);

    const int kv0 = t * 64;
    const bool active = (kv0 <= qhi);
    const bool domask = active && (kv0 + 63 > qlo);

    if (active) {
      f4_t sacc[2][4];
#pragma unroll
      for (int rg = 0; rg < 2; ++rg)
#pragma unroll
        for (int cf = 0; cf < 4; ++cf) sacc[rg][cf] = (f4_t){0.f, 0.f, 0.f, 0.f};
      __builtin_amdgcn_s_setprio(1);
#pragma unroll
      for (int cf = 0; cf < 4; ++cf)
#pragma unroll
        for (int kc = 0; kc < 4; ++kc) {
          int krow = cf * 16 + rsel;
          bf8_t bk = *(const bf8_t*)&Ks[curK][krow * 128 + ((kc * 32 + kof) ^ ((krow & 7) << 3))];
          sacc[0][cf] = __builtin_amdgcn_mfma_f32_16x16x32_bf16(aq[0][kc], bk, sacc[0][cf], 0, 0, 0);
          sacc[1][cf] = __builtin_amdgcn_mfma_f32_16x16x32_bf16(aq[1][kc], bk, sacc[1][cf], 0, 0, 0);
        }
      __builtin_amdgcn_s_setprio(0);

      if (domask) {
#pragma unroll
        for (int rg = 0; rg < 2; ++rg)
#pragma unroll
          for (int cf = 0; cf < 4; ++cf) {
            int kvabs = kv0 + cf * 16 + rsel;
#pragma unroll
            for (int r = 0; r < 4; ++r) {
              int qabs = qlo + rg * 16 + qr0 + r;
              if (kvabs > qabs) sacc[rg][cf][r] = -3e30f;
            }
          }
      }

      float tmr[2][4];
      bool needr = false;
#pragma unroll
      for (int rg = 0; rg < 2; ++rg)
#pragma unroll
        for (int r = 0; r < 4; ++r) {
          tmr[rg][r] = fmaxf(fmaxf(sacc[rg][0][r], sacc[rg][1][r]),
                             fmaxf(sacc[rg][2][r], sacc[rg][3][r]));
          needr = needr || (tmr[rg][r] > mrow[rg][r] + 11.f);
        }
      if (__any(needr)) {
#pragma unroll
        for (int rg = 0; rg < 2; ++rg)
#pragma unroll
          for (int r = 0; r < 4; ++r) {
            float m = tmr[rg][r];
#pragma unroll
            for (int d = 1; d < 16; d <<= 1) m = fmaxf(m, __shfl_xor(m, d, 16));
            float nm = fmaxf(mrow[rg][r], m);
            float sc = exp2f(mrow[rg][r] - nm);
            mrow[rg][r] = nm;
#pragma unroll
            for (int nf = 0; nf < 9; ++nf) o[rg][nf][r] *= sc;
          }
      }
#pragma unroll
      for (int rg = 0; rg < 2; ++rg)
#pragma unroll
        for (int cf = 0; cf < 4; ++cf)
#pragma unroll
          for (int r = 0; r < 4; ++r)
            sacc[rg][cf][r] = exp2f(sacc[rg][cf][r] - mrow[rg][r]);

      unsigned short* P = &Pw[wv][0];
#pragma unroll
      for (int rg = 0; rg < 2; ++rg)
#pragma unroll
        for (int cf = 0; cf < 4; ++cf)
#pragma unroll
          for (int r = 0; r < 4; ++r) {
            int prow = rg * 16 + qr0 + r;
            P[prow * 64 + ((cf * 16 + rsel) ^ (((prow >> 1) & 7) << 3))] = f2bf(sacc[rg][cf][r]);
          }
    }

    if (pfV) VTWRITE(curV ^ 1);

    if (active) {
      unsigned short* P = &Pw[wv][0];
      __builtin_amdgcn_s_setprio(1);
#pragma unroll
      for (int kc2 = 0; kc2 < 2; ++kc2) {
        bf8_t pa0, pa1;
        {
          int pr0 = rsel;           // rg 0
          int pr1 = 16 + rsel;      // rg 1
          pa0 = *(const bf8_t*)&P[pr0 * 64 + ((kc2 * 32 + kof) ^ (((pr0 >> 1) & 7) << 3))];
          pa1 = *(const bf8_t*)&P[pr1 * 64 + ((kc2 * 32 + kof) ^ (((pr1 >> 1) & 7) << 3))];
        }
#pragma unroll
        for (int nf = 0; nf < 8; ++nf) {
          int vrow = nf * 16 + rsel;
          bf8_t bv = *(const bf8_t*)&Vt[curV][vrow * 64 + ((kc2 * 32 + kof) ^ ((vrow & 7) << 3))];
          o[0][nf] = __builtin_amdgcn_mfma_f32_16x16x32_bf16(pa0, bv, o[0][nf], 0, 0, 0);
          o[1][nf] = __builtin_amdgcn_mfma_f32_16x16x32_bf16(pa1, bv, o[1][nf], 0, 0, 0);
        }
        o[0][8] = __builtin_amdgcn_mfma_f32_16x16x32_bf16(pa0, vones, o[0][8], 0, 0, 0);
        o[1][8] = __builtin_amdgcn_mfma_f32_16x16x32_bf16(pa1, vones, o[1][8], 0, 0, 0);
      }
      __builtin_amdgcn_s_setprio(0);
    }
  }
#undef KSTAGE
#undef VTWRITE

  const int b = bh >> 4, h = bh & 15;
#pragma unroll
  for (int rg = 0; rg < 2; ++rg)
#pragma unroll
    for (int r = 0; r < 4; ++r) {
      float inv = 1.0f / o[rg][8][r];
      int s = qlo + rg * 16 + qr0 + r;
      size_t rowo = ((size_t)b * S_ + s) * D_ + h * DH_;
#pragma unroll
      for (int nf = 0; nf < 8; ++nf)
        Z[rowo + nf * 16 + rsel] = f2bf(o[rg][nf][r] * inv);
    }
}

// ---------------- orchestration ----------------
extern "C" void kernel_launch(void* const* d_in, const int* in_sizes, int n_in,
                              void* d_out, int out_size, void* d_ws, size_t ws_size,
                              hipStream_t stream) {
  const float* x    = (const float*)d_in[0];
  const float* Wqkv = (const float*)d_in[1];
  const float* Wo   = (const float*)d_in[2];
  float* out = (float*)d_out;

  const size_t QKV_ELEMS = (size_t)B_ * H_ * S_ * DH_;
  char* w = (char*)d_ws;
  unsigned short* xb = (unsigned short*)w;   // x bf16; z aliases it later
  unsigned short* z  = xb;
  w += (size_t)8192 * 2048 * 2;
  unsigned short* wqkvb = (unsigned short*)w; w += (size_t)6144 * 2048 * 2;
  unsigned short* wob   = (unsigned short*)w; w += (size_t)2048 * 2048 * 2;
  unsigned short* qq = (unsigned short*)w;    w += QKV_ELEMS * 2;
  unsigned short* kk = (unsigned short*)w;    w += QKV_ELEMS * 2;
  unsigned short* vv = (unsigned short*)w;    w += QKV_ELEMS * 2;
  float* tabc = (float*)w; w += (size_t)S_ * 64 * 4;
  float* tabs = (float*)w; w += (size_t)S_ * 64 * 4;
  if ((size_t)(w - (char*)d_ws) > ws_size) return;

  conv_all<<<2048, 256, 0, stream>>>(x, Wqkv, Wo, xb, wqkvb, wob);
  gemm256<1><<<dim3(24, 32), 512, 0, stream>>>(xb, wqkvb, nullptr, qq, 8192, 6144, 2048);
  rope_tab<<<2048, 64, 0, stream>>>(tabc, tabs);
  rope_k<<<4096, 256, 0, stream>>>(kk, tabc, tabs);
  attn_fwd<<<dim3(S_ / 256, B_ * H_), 512, 0, stream>>>(qq, kk, vv, z, tabc, tabs);
  gemm256<0><<<dim3(8, 32), 512, 0, stream>>>(z, wob, out, nullptr, 8192, 2048, 2048);
}

// Round 19
// 407.406 us; speedup vs baseline: 1.0705x; 1.0705x over previous
//
#include <hip/hip_runtime.h>
#include <hip/hip_bf16.h>
#include <stdint.h>

#define B_ 4
#define S_ 2048
#define D_ 2048
#define H_ 16
#define DH_ 128

typedef short bf8_t __attribute__((ext_vector_type(8)));   // 8 bf16 (4 VGPRs)
typedef float f4_t  __attribute__((ext_vector_type(4)));   // MFMA C/D

__device__ __forceinline__ unsigned short f2bf(float f) {
  __hip_bfloat16 h = __float2bfloat16(f);   // RNE
  return *reinterpret_cast<const unsigned short*>(&h);
}
__device__ __forceinline__ float bf2f(unsigned short u) {
  return __uint_as_float(((unsigned int)u) << 16);
}

// async global->LDS, 16B per lane. LDS dest must be (wave-uniform base + lane*16).
__device__ __forceinline__ void gload_lds16(const void* g, void* lds) {
  __builtin_amdgcn_global_load_lds(
      (const __attribute__((address_space(1))) unsigned int*)(uintptr_t)g,
      (__attribute__((address_space(3))) unsigned int*)(unsigned int)(uintptr_t)lds,
      16, 0, 0);
}

// ---------------- fused f32 -> bf16 conversion, grid-stride ----------------
__global__ __launch_bounds__(256) void conv_all(
    const float* __restrict__ x, const float* __restrict__ wqkv,
    const float* __restrict__ wo, unsigned short* __restrict__ xb,
    unsigned short* __restrict__ wqkvb, unsigned short* __restrict__ wob) {
  const int NX = 4194304, NQ = 3145728;
  const int TOT = 8388608, STR = 2048 * 256;
  for (int idx = blockIdx.x * 256 + threadIdx.x; idx < TOT; idx += STR) {
    const float* in;
    unsigned short* out;
    int i;
    if (idx < NX)           { in = x;    out = xb;    i = idx; }
    else if (idx < NX + NQ) { in = wqkv; out = wqkvb; i = idx - NX; }
    else                    { in = wo;   out = wob;   i = idx - NX - NQ; }
    float4 v = ((const float4*)in)[i];
    ushort4 u;
    u.x = f2bf(v.x); u.y = f2bf(v.y); u.z = f2bf(v.z); u.w = f2bf(v.w);
    ((ushort4*)out)[i] = u;
  }
}

// ============ 8-phase 256x256 GEMM (m201 port, verified ledger), BK=64 ============
// Every tile confirmed (vmcnt+barrier) in an EARLIER phase than the one
// reading it; see r17. ~195 us QKV, MfmaUtil 46.5%, 0 bank conflicts.
template <int EPI>
__global__ __launch_bounds__(512, 2) void gemm8p(
    const unsigned short* __restrict__ A, const unsigned short* __restrict__ Bt,
    float* __restrict__ Cf, unsigned short* __restrict__ Cb,
    int M, int N, int K) {
  __shared__ unsigned short LDSm[2][2][2][8192];   // [buf][A/B][half][16KB] = 128 KB
  const int tid  = threadIdx.x;
  const int lane = tid & 63;
  const int wv   = tid >> 6;     // 0..7
  const int wr   = wv >> 2;      // 0..1  (M half)
  const int wc   = wv & 3;       // 0..3  (N quarter)
  const int rsel = lane & 15;
  const int g    = lane >> 4;
  const int qr0  = g * 4;

  // bijective XCD swizzle (nwg % 8 == 0)
  int id  = blockIdx.y * gridDim.x + blockIdx.x;
  int cpx = (gridDim.x * gridDim.y) >> 3;
  int swz = (id & 7) * cpx + (id >> 3);
  const int bm = (swz / gridDim.x) * 256;
  const int bn = (swz % gridDim.x) * 256;

  const int NT = K >> 6;   // BK=64 tiles (even, >= 4)
  const int NI = NT >> 1;

  // fragment-read swizzled k-offsets (granule G = (ks*4+g) ^ (rsel&7))
  const int sz0 = ((g) ^ (rsel & 7)) << 4;
  const int sz1 = ((4 + g) ^ (rsel & 7)) << 4;

  f4_t acc[8][4];
#pragma unroll
  for (int i = 0; i < 8; ++i)
#pragma unroll
    for (int j = 0; j < 4; ++j) acc[i][j] = (f4_t){0.f, 0.f, 0.f, 0.f};

  bf8_t af[2][2];     // A-frags of current quarter [i2][ks]
  bf8_t bfr[4][2];    // B-frags of current tile    [j][ks]

#define STG(m_, h_, X_)                                                       \
  {                                                                           \
    const unsigned short* P_ = (m_ == 0) ? A : Bt;                            \
    int rb_ = (m_ == 0) ? bm : bn;                                            \
    _Pragma("unroll")                                                         \
    for (int u_ = 0; u_ < 2; ++u_) {                                          \
      int ob_  = (u_ * 512 + tid) * 16;                                       \
      int row_ = ob_ >> 7;                                                    \
      int G_   = ((ob_ >> 4) & 7) ^ (row_ & 7);                               \
      gload_lds16(P_ + (size_t)(rb_ + (h_) * 128 + row_) * K + (X_) * 64 + G_ * 8, \
                  (char*)&LDSm[(X_) & 1][m_][h_][0] + ob_);                   \
    }                                                                         \
  }
#define RD_A(bu_, q_)                                                         \
  {                                                                           \
    const char* Ab_ = (const char*)&LDSm[bu_][0][wr][0];                      \
    af[0][0] = *(const bf8_t*)(Ab_ + ((q_) * 32 + rsel) * 128 + sz0);         \
    af[0][1] = *(const bf8_t*)(Ab_ + ((q_) * 32 + rsel) * 128 + sz1);         \
    af[1][0] = *(const bf8_t*)(Ab_ + ((q_) * 32 + 16 + rsel) * 128 + sz0);    \
    af[1][1] = *(const bf8_t*)(Ab_ + ((q_) * 32 + 16 + rsel) * 128 + sz1);    \
  }
#define RD_B(bu_)                                                             \
  {                                                                           \
    const char* Bb_ = (const char*)&LDSm[bu_][1][wc >> 1][0];                 \
    _Pragma("unroll")                                                         \
    for (int j_ = 0; j_ < 4; ++j_) {                                          \
      int rlb_ = (wc & 1) * 64 + j_ * 16 + rsel;                              \
      bfr[j_][0] = *(const bf8_t*)(Bb_ + rlb_ * 128 + sz0);                   \
      bfr[j_][1] = *(const bf8_t*)(Bb_ + rlb_ * 128 + sz1);                   \
    }                                                                         \
  }
#define MM(q_)                                                                \
  __builtin_amdgcn_s_setprio(1);                                              \
  _Pragma("unroll")                                                           \
  for (int i2_ = 0; i2_ < 2; ++i2_)                                           \
    _Pragma("unroll")                                                         \
    for (int j_ = 0; j_ < 4; ++j_) {                                          \
      acc[(q_) * 2 + i2_][j_] = __builtin_amdgcn_mfma_f32_16x16x32_bf16(      \
          af[i2_][0], bfr[j_][0], acc[(q_) * 2 + i2_][j_], 0, 0, 0);          \
      acc[(q_) * 2 + i2_][j_] = __builtin_amdgcn_mfma_f32_16x16x32_bf16(      \
          af[i2_][1], bfr[j_][1], acc[(q_) * 2 + i2_][j_], 0, 0, 0);          \
    }                                                                         \
  __builtin_amdgcn_s_setprio(0);
#define BAR() { __builtin_amdgcn_s_barrier(); asm volatile("" ::: "memory"); }

  // prologue: B(0) h0,h1; A(0) h0,h1; B(1) h0,h1; CONFIRM tile 0; barrier.
  STG(1, 0, 0); STG(1, 1, 0); STG(0, 0, 0); STG(0, 1, 0);
  STG(1, 0, 1); STG(1, 1, 1);
  asm volatile("s_waitcnt vmcnt(4)" ::: "memory");   // oldest 8 = tile 0
  BAR();

  for (int it = 0; it < NI; ++it) {
    const int T = it * 2;
    const bool c2 = (T + 2 < NT);   // == (T+3 < NT), NT even

    // ---- p0 (reads tile T, confirmed at prev p7 / prologue) ----
    RD_A(0, 0); RD_B(0);
    STG(0, 0, T + 1);
    BAR(); MM(0); BAR();
    // ---- p1 ----
    RD_A(0, 1);
    STG(0, 1, T + 1);
    BAR(); MM(1); BAR();
    // ---- p2 ----
    RD_A(0, 2);
    if (c2) STG(1, 0, T + 2);
    BAR(); MM(2); BAR();
    // ---- p3: confirm tile T+1 before p4 reads it ----
    RD_A(0, 3);
    if (c2) { STG(1, 1, T + 2); asm volatile("s_waitcnt vmcnt(4)" ::: "memory"); }
    else    { asm volatile("s_waitcnt vmcnt(0)" ::: "memory"); }
    BAR(); MM(3); BAR();
    // ---- p4 (reads tile T+1) ----
    RD_A(1, 0); RD_B(1);
    if (c2) STG(0, 0, T + 2);
    BAR(); MM(0); BAR();
    // ---- p5 ----
    RD_A(1, 1);
    if (c2) STG(0, 1, T + 2);
    BAR(); MM(1); BAR();
    // ---- p6 ----
    RD_A(1, 2);
    if (c2) STG(1, 0, T + 3);
    BAR(); MM(2); BAR();
    // ---- p7: confirm tile T+2 for the next iteration ----
    RD_A(1, 3);
    if (c2) { STG(1, 1, T + 3); asm volatile("s_waitcnt vmcnt(4)" ::: "memory"); }
    BAR(); MM(3); BAR();
  }
#undef STG
#undef RD_A
#undef RD_B
#undef MM
#undef BAR

#pragma unroll
  for (int i = 0; i < 8; ++i) {
#pragma unroll
    for (int j = 0; j < 4; ++j) {
#pragma unroll
      for (int r = 0; r < 4; ++r) {
        int row = bm + wr * 128 + i * 16 + qr0 + r;
        int col = bn + wc * 64 + j * 16 + rsel;
        float v = acc[i][j][r];
        if (EPI == 0) {
          Cf[(size_t)row * N + col] = v;
        } else {
          int c = col >> 11, h = (col >> 7) & (H_ - 1), dh = col & (DH_ - 1);
          int b = row >> 11, s = row & (S_ - 1);
          size_t dst = ((((size_t)c * B_ + b) * H_ + h) * S_ + s) * DH_ + dh;
          Cb[dst] = f2bf(v);
        }
      }
    }
  }
}

// ---------------- 256x256 GEMM, ring-4 BK=32 (proven r11; out-proj) ----------
template <int EPI>
__global__ __launch_bounds__(512, 2) void gemm256(
    const unsigned short* __restrict__ A, const unsigned short* __restrict__ Bt,
    float* __restrict__ Cf, unsigned short* __restrict__ Cb,
    int M, int N, int K) {
  __shared__ unsigned short AB[4][2][8192];
  const int tid  = threadIdx.x;
  const int lane = tid & 63;
  const int wv   = tid >> 6;
  const int wr   = wv >> 2;
  const int wc   = wv & 3;
  const int rsel = lane & 15;
  const int g    = lane >> 4;
  const int qr0  = g * 4;

  int id  = blockIdx.y * gridDim.x + blockIdx.x;
  int cpx = (gridDim.x * gridDim.y) >> 3;
  int swz = (id & 7) * cpx + (id >> 3);
  const int bm = (swz / gridDim.x) * 256;
  const int bn = (swz % gridDim.x) * 256;

  const int NS = K >> 5;

  const int ob0 = tid * 16, ob1 = ob0 + 8192;
  const int row0 = ob0 >> 6, row1 = ob1 >> 6;
  const int g0 = ((ob0 >> 4) & 3) ^ ((row0 >> 1) & 3);
  const int g1 = ((ob1 >> 4) & 3) ^ ((row1 >> 1) & 3);
  const unsigned short* Ag0 = A + (size_t)(bm + row0) * K + g0 * 8;
  const unsigned short* Ag1 = A + (size_t)(bm + row1) * K + g1 * 8;
  const unsigned short* Bg0 = Bt + (size_t)(bn + row0) * K + g0 * 8;
  const unsigned short* Bg1 = Bt + (size_t)(bn + row1) * K + g1 * 8;

  f4_t acc[8][4];
#pragma unroll
  for (int i = 0; i < 8; ++i)
#pragma unroll
    for (int j = 0; j < 4; ++j) acc[i][j] = (f4_t){0.f, 0.f, 0.f, 0.f};

  int aoff[8], boff[4];
#pragma unroll
  for (int i = 0; i < 8; ++i) {
    int arow = wr * 128 + i * 16 + rsel;
    aoff[i] = arow * 64 + ((g * 16) ^ ((arow & 6) << 3));
  }
#pragma unroll
  for (int j = 0; j < 4; ++j) {
    int brow = wc * 64 + j * 16 + rsel;
    boff[j] = brow * 64 + ((g * 16) ^ ((brow & 6) << 3));
  }

#define STAGE(sl)                                                        \
  {                                                                      \
    int slot_ = (sl) & 3;                                                \
    int ks_   = (sl) << 5;                                               \
    gload_lds16(Ag0 + ks_, (char*)&AB[slot_][0][0] + ob0);               \
    gload_lds16(Ag1 + ks_, (char*)&AB[slot_][0][0] + ob1);               \
    gload_lds16(Bg0 + ks_, (char*)&AB[slot_][1][0] + ob0);               \
    gload_lds16(Bg1 + ks_, (char*)&AB[slot_][1][0] + ob1);               \
  }

  STAGE(0); STAGE(1); STAGE(2);

  for (int s = 0; s < NS; ++s) {
    if (s < NS - 2)       asm volatile("s_waitcnt vmcnt(8)" ::: "memory");
    else if (s == NS - 2) asm volatile("s_waitcnt vmcnt(4)" ::: "memory");
    else                  asm volatile("s_waitcnt vmcnt(0)" ::: "memory");
    __builtin_amdgcn_s_barrier();
    asm volatile("" ::: "memory");

    const char* As_ = (const char*)&AB[s & 3][0][0];
    const char* Bs_ = (const char*)&AB[s & 3][1][0];
    bf8_t af[8], bfr[4];
#pragma unroll
    for (int i = 0; i < 8; ++i) af[i] = *(const bf8_t*)(As_ + aoff[i]);
#pragma unroll
    for (int j = 0; j < 4; ++j) bfr[j] = *(const bf8_t*)(Bs_ + boff[j]);

    if (s + 3 < NS) STAGE(s + 3);

    __builtin_amdgcn_s_setprio(1);
#pragma unroll
    for (int i = 0; i < 8; ++i)
#pragma unroll
      for (int j = 0; j < 4; ++j)
        acc[i][j] = __builtin_amdgcn_mfma_f32_16x16x32_bf16(af[i], bfr[j], acc[i][j], 0, 0, 0);
    __builtin_amdgcn_s_setprio(0);
  }
#undef STAGE

#pragma unroll
  for (int i = 0; i < 8; ++i) {
#pragma unroll
    for (int j = 0; j < 4; ++j) {
#pragma unroll
      for (int r = 0; r < 4; ++r) {
        int row = bm + wr * 128 + i * 16 + qr0 + r;
        int col = bn + wc * 64 + j * 16 + rsel;
        float v = acc[i][j][r];
        if (EPI == 0) {
          Cf[(size_t)row * N + col] = v;
        } else {
          int c = col >> 11, h = (col >> 7) & (H_ - 1), dh = col & (DH_ - 1);
          int b = row >> 11, s = row & (S_ - 1);
          size_t dst = ((((size_t)c * B_ + b) * H_ + h) * S_ + s) * DH_ + dh;
          Cb[dst] = f2bf(v);
        }
      }
    }
  }
}

// ---------------- RoPE tables ----------------
__global__ void rope_tab(float* __restrict__ tc, float* __restrict__ ts) {
  int s = blockIdx.x;
  int i = threadIdx.x;   // 64 threads
  float inv = powf(10000.0f, -(float)i / 64.0f);
  float f   = (float)s * inv;
  tc[s * 64 + i] = cosf(f);
  ts[s * 64 + i] = sinf(f);
}

// ---------------- RoPE apply in-place on K only, bf16x8 vectorized ----------
__global__ __launch_bounds__(256) void rope_k(
    unsigned short* __restrict__ Kk,
    const float* __restrict__ tc, const float* __restrict__ ts) {
  int idx = blockIdx.x * 256 + threadIdx.x;   // 2^20 total
  int iv  = idx & 7;
  int s   = (idx >> 3) & (S_ - 1);
  int bh  = idx >> 14;                        // 0..63
  size_t base = ((size_t)bh * S_ + s) * DH_;
  int i0 = iv * 8;
  bf8_t x1 = *(const bf8_t*)&Kk[base + i0];
  bf8_t x2 = *(const bf8_t*)&Kk[base + i0 + 64];
  const float* tcp = tc + s * 64 + i0;
  const float* tsp = ts + s * 64 + i0;
  bf8_t y1, y2;
#pragma unroll
  for (int e = 0; e < 8; ++e) {
    float c = tcp[e], sn = tsp[e];
    float a = bf2f((unsigned short)x1[e]);
    float b = bf2f((unsigned short)x2[e]);
    y1[e] = (short)f2bf(a * c - b * sn);
    y2[e] = (short)f2bf(b * c + a * sn);
  }
  *(bf8_t*)&Kk[base + i0]      = y1;
  *(bf8_t*)&Kk[base + i0 + 64] = y2;
}

// ---------------- causal flash attention (r11 structure, Q-RoPE fused) ----
// Descending chunk order (LPT): with greedy dynamic dispatch and 2 blocks/CU,
// longest-first is near-optimal (r18's "balanced pairs" regressed 28 us).
__global__ __launch_bounds__(512) void attn_fwd(
    const unsigned short* __restrict__ Q, const unsigned short* __restrict__ Kk,
    const unsigned short* __restrict__ V, unsigned short* __restrict__ Z,
    const float* __restrict__ tabc, const float* __restrict__ tabs) {
  __shared__ unsigned short Ks[3][64 * 128];  // 48 KB ring, XOR-swizzled (src-side)
  __shared__ unsigned short Vt[2][128 * 64];  // 32 KB, [dh][kv], XOR-swizzled
  __shared__ unsigned short Pw[8][32 * 64];   // 32 KB, per-wave 32 rows, swizzled
  const int tid  = threadIdx.x;
  const int lane = tid & 63;
  const int wv   = tid >> 6;                  // 0..7

  int id  = blockIdx.y * gridDim.x + blockIdx.x;   // nwg = 512
  int x   = id & 7;
  int idx = id >> 3;                               // 0..63
  const int bh = x * 8 + (idx & 7);
  const int q0 = (7 - (idx >> 3)) * 256;

  const size_t base = (size_t)bh * S_ * DH_;
  const int rsel = lane & 15;
  const int g    = lane >> 4;
  const int kof  = g * 8;
  const int qr0  = g * 4;
  const int qlo  = q0 + wv * 32;
  const int qhi  = qlo + 31;
  const float sl2 = 0.08838834764831845f * 1.4426950408889634f;  // scale*log2(e)

  // Q A-frags for both row-groups: load raw, RoPE in-register, fold sl2.
  bf8_t aq[2][4];
#pragma unroll
  for (int rg = 0; rg < 2; ++rg) {
    const int qrow = qlo + rg * 16 + rsel;
#pragma unroll
    for (int kc = 0; kc < 4; ++kc)
      aq[rg][kc] = *(const bf8_t*)&Q[base + (size_t)qrow * DH_ + kc * 32 + kof];
    const float* tcr = tabc + (size_t)qrow * 64;
    const float* tsr = tabs + (size_t)qrow * 64;
#pragma unroll
    for (int kc = 0; kc < 2; ++kc)
#pragma unroll
      for (int e = 0; e < 8; ++e) {
        int i = kc * 32 + kof + e;   // dh in [0,64)
        float c  = tcr[i], sn = tsr[i];
        float x1 = bf2f((unsigned short)aq[rg][kc][e]);
        float x2 = bf2f((unsigned short)aq[rg][kc + 2][e]);
        aq[rg][kc][e]     = (short)f2bf((x1 * c - x2 * sn) * sl2);
        aq[rg][kc + 2][e] = (short)f2bf((x2 * c + x1 * sn) * sl2);
      }
  }

  bf8_t vones;
#pragma unroll
  for (int e = 0; e < 8; ++e) vones[e] = (short)0x3F80;

  f4_t o[2][9];   // [rg][0..7]=output frags, [rg][8]=row-sum (denominator)
#pragma unroll
  for (int rg = 0; rg < 2; ++rg)
#pragma unroll
    for (int nf = 0; nf < 9; ++nf) o[rg][nf] = (f4_t){0.f, 0.f, 0.f, 0.f};
  float mrow[2][4] = {{-3e30f, -3e30f, -3e30f, -3e30f},
                      {-3e30f, -3e30f, -3e30f, -3e30f}};
  const int nt = q0 / 64 + 4;   // kv tiles cover [0, q0+256); nt >= 4

  const int kvp = tid & 31;
  const int vc0 = (tid >> 5) * 8;

#define KSTAGE(tt)                                                            \
  {                                                                           \
    const unsigned short* gK_ = Kk + base + (size_t)(tt) * 64 * DH_;          \
    int slot_ = (tt) % 3;                                                     \
    _Pragma("unroll")                                                         \
    for (int c = 0; c < 2; ++c) {                                             \
      int ob = (c * 512 + tid) * 16;                                          \
      int row = ob >> 8;                                                      \
      int scol = (ob & 255) ^ ((row & 7) << 4);                               \
      gload_lds16(gK_ + (size_t)row * DH_ + (scol >> 1),                      \
                  (char*)&Ks[slot_][0] + ob);                                 \
    }                                                                         \
  }
#define VTWRITE(buf_)                                                         \
  {                                                                           \
    unsigned int* Vt32 = (unsigned int*)&Vt[buf_][0];                         \
    _Pragma("unroll")                                                         \
    for (int e = 0; e < 8; ++e) {                                             \
      unsigned int val = (unsigned short)vlo[e] |                             \
                         ((unsigned int)(unsigned short)vhi[e] << 16);        \
      Vt32[(vc0 + e) * 32 + (kvp ^ (e << 2))] = val;                          \
    }                                                                         \
  }

  bf8_t vlo, vhi;
  vlo = *(const bf8_t*)&V[base + (size_t)(2 * kvp) * DH_ + vc0];
  vhi = *(const bf8_t*)&V[base + (size_t)(2 * kvp + 1) * DH_ + vc0];
  KSTAGE(0);
  KSTAGE(1);              // nt >= 4 always
  VTWRITE(0);             // compiler waits V(0) only; K loads stay in flight

  for (int t = 0; t < nt; ++t) {
    const int curV = t & 1;
    const int curK = t % 3;
    const bool pfV = (t + 1 < nt);
    const bool pfK = (t + 2 < nt);

    if (pfV) asm volatile("s_waitcnt vmcnt(2)" ::: "memory");
    else     asm volatile("s_waitcnt vmcnt(0)" ::: "memory");
    asm volatile("s_waitcnt lgkmcnt(0)" ::: "memory");
    __builtin_amdgcn_s_barrier();
    asm volatile("" ::: "memory");

    if (pfV) {
      const unsigned short* gV = V + base + (size_t)(t + 1) * 64 * DH_;
      vlo = *(const bf8_t*)&gV[(size_t)(2 * kvp) * DH_ + vc0];
      vhi = *(const bf8_t*)&gV[(size_t)(2 * kvp + 1) * DH_ + vc0];
    }
    if (pfK) KSTAGE(t + 2);

    const int kv0 = t * 64;
    const bool active = (kv0 <= qhi);
    const bool domask = active && (kv0 + 63 > qlo);

    if (active) {
      f4_t sacc[2][4];
#pragma unroll
      for (int rg = 0; rg < 2; ++rg)
#pragma unroll
        for (int cf = 0; cf < 4; ++cf) sacc[rg][cf] = (f4_t){0.f, 0.f, 0.f, 0.f};
      __builtin_amdgcn_s_setprio(1);
#pragma unroll
      for (int cf = 0; cf < 4; ++cf)
#pragma unroll
        for (int kc = 0; kc < 4; ++kc) {
          int krow = cf * 16 + rsel;
          bf8_t bk = *(const bf8_t*)&Ks[curK][krow * 128 + ((kc * 32 + kof) ^ ((krow & 7) << 3))];
          sacc[0][cf] = __builtin_amdgcn_mfma_f32_16x16x32_bf16(aq[0][kc], bk, sacc[0][cf], 0, 0, 0);
          sacc[1][cf] = __builtin_amdgcn_mfma_f32_16x16x32_bf16(aq[1][kc], bk, sacc[1][cf], 0, 0, 0);
        }
      __builtin_amdgcn_s_setprio(0);

      if (domask) {
#pragma unroll
        for (int rg = 0; rg < 2; ++rg)
#pragma unroll
          for (int cf = 0; cf < 4; ++cf) {
            int kvabs = kv0 + cf * 16 + rsel;
#pragma unroll
            for (int r = 0; r < 4; ++r) {
              int qabs = qlo + rg * 16 + qr0 + r;
              if (kvabs > qabs) sacc[rg][cf][r] = -3e30f;
            }
          }
      }

      float tmr[2][4];
      bool needr = false;
#pragma unroll
      for (int rg = 0; rg < 2; ++rg)
#pragma unroll
        for (int r = 0; r < 4; ++r) {
          tmr[rg][r] = fmaxf(fmaxf(sacc[rg][0][r], sacc[rg][1][r]),
                             fmaxf(sacc[rg][2][r], sacc[rg][3][r]));
          needr = needr || (tmr[rg][r] > mrow[rg][r] + 11.f);
        }
      if (__any(needr)) {
#pragma unroll
        for (int rg = 0; rg < 2; ++rg)
#pragma unroll
          for (int r = 0; r < 4; ++r) {
            float m = tmr[rg][r];
#pragma unroll
            for (int d = 1; d < 16; d <<= 1) m = fmaxf(m, __shfl_xor(m, d, 16));
            float nm = fmaxf(mrow[rg][r], m);
            float sc = exp2f(mrow[rg][r] - nm);
            mrow[rg][r] = nm;
#pragma unroll
            for (int nf = 0; nf < 9; ++nf) o[rg][nf][r] *= sc;
          }
      }
#pragma unroll
      for (int rg = 0; rg < 2; ++rg)
#pragma unroll
        for (int cf = 0; cf < 4; ++cf)
#pragma unroll
          for (int r = 0; r < 4; ++r)
            sacc[rg][cf][r] = exp2f(sacc[rg][cf][r] - mrow[rg][r]);

      unsigned short* P = &Pw[wv][0];
#pragma unroll
      for (int rg = 0; rg < 2; ++rg)
#pragma unroll
        for (int cf = 0; cf < 4; ++cf)
#pragma unroll
          for (int r = 0; r < 4; ++r) {
            int prow = rg * 16 + qr0 + r;
            P[prow * 64 + ((cf * 16 + rsel) ^ (((prow >> 1) & 7) << 3))] = f2bf(sacc[rg][cf][r]);
          }
    }

    if (pfV) VTWRITE(curV ^ 1);

    if (active) {
      unsigned short* P = &Pw[wv][0];
      __builtin_amdgcn_s_setprio(1);
#pragma unroll
      for (int kc2 = 0; kc2 < 2; ++kc2) {
        bf8_t pa0, pa1;
        {
          int pr0 = rsel;           // rg 0
          int pr1 = 16 + rsel;      // rg 1
          pa0 = *(const bf8_t*)&P[pr0 * 64 + ((kc2 * 32 + kof) ^ (((pr0 >> 1) & 7) << 3))];
          pa1 = *(const bf8_t*)&P[pr1 * 64 + ((kc2 * 32 + kof) ^ (((pr1 >> 1) & 7) << 3))];
        }
#pragma unroll
        for (int nf = 0; nf < 8; ++nf) {
          int vrow = nf * 16 + rsel;
          bf8_t bv = *(const bf8_t*)&Vt[curV][vrow * 64 + ((kc2 * 32 + kof) ^ ((vrow & 7) << 3))];
          o[0][nf] = __builtin_amdgcn_mfma_f32_16x16x32_bf16(pa0, bv, o[0][nf], 0, 0, 0);
          o[1][nf] = __builtin_amdgcn_mfma_f32_16x16x32_bf16(pa1, bv, o[1][nf], 0, 0, 0);
        }
        o[0][8] = __builtin_amdgcn_mfma_f32_16x16x32_bf16(pa0, vones, o[0][8], 0, 0, 0);
        o[1][8] = __builtin_amdgcn_mfma_f32_16x16x32_bf16(pa1, vones, o[1][8], 0, 0, 0);
      }
      __builtin_amdgcn_s_setprio(0);
    }
  }
#undef KSTAGE
#undef VTWRITE

  const int b = bh >> 4, h = bh & 15;
#pragma unroll
  for (int rg = 0; rg < 2; ++rg)
#pragma unroll
    for (int r = 0; r < 4; ++r) {
      float inv = 1.0f / o[rg][8][r];
      int s = qlo + rg * 16 + qr0 + r;
      size_t rowo = ((size_t)b * S_ + s) * D_ + h * DH_;
#pragma unroll
      for (int nf = 0; nf < 8; ++nf)
        Z[rowo + nf * 16 + rsel] = f2bf(o[rg][nf][r] * inv);
    }
}

// ---------------- orchestration ----------------
extern "C" void kernel_launch(void* const* d_in, const int* in_sizes, int n_in,
                              void* d_out, int out_size, void* d_ws, size_t ws_size,
                              hipStream_t stream) {
  const float* x    = (const float*)d_in[0];
  const float* Wqkv = (const float*)d_in[1];
  const float* Wo   = (const float*)d_in[2];
  float* out = (float*)d_out;

  const size_t QKV_ELEMS = (size_t)B_ * H_ * S_ * DH_;
  char* w = (char*)d_ws;
  unsigned short* xb = (unsigned short*)w;   // x bf16; z aliases it later
  unsigned short* z  = xb;
  w += (size_t)8192 * 2048 * 2;
  unsigned short* wqkvb = (unsigned short*)w; w += (size_t)6144 * 2048 * 2;
  unsigned short* wob   = (unsigned short*)w; w += (size_t)2048 * 2048 * 2;
  unsigned short* qq = (unsigned short*)w;    w += QKV_ELEMS * 2;
  unsigned short* kk = (unsigned short*)w;    w += QKV_ELEMS * 2;
  unsigned short* vv = (unsigned short*)w;    w += QKV_ELEMS * 2;
  float* tabc = (float*)w; w += (size_t)S_ * 64 * 4;
  float* tabs = (float*)w; w += (size_t)S_ * 64 * 4;
  if ((size_t)(w - (char*)d_ws) > ws_size) return;

  conv_all<<<2048, 256, 0, stream>>>(x, Wqkv, Wo, xb, wqkvb, wob);
  gemm8p<1><<<dim3(24, 32), 512, 0, stream>>>(xb, wqkvb, nullptr, qq, 8192, 6144, 2048);
  rope_tab<<<2048, 64, 0, stream>>>(tabc, tabs);
  rope_k<<<4096, 256, 0, stream>>>(kk, tabc, tabs);
  attn_fwd<<<dim3(S_ / 256, B_ * H_), 512, 0, stream>>>(qq, kk, vv, z, tabc, tabs);
  gemm256<0><<<dim3(8, 32), 512, 0, stream>>>(z, wob, out, nullptr, 8192, 2048, 2048);
}